// Round 16
// baseline (470.638 us; speedup 1.0000x reference)
//
#include <hip/hip_runtime.h>

// Dims (fixed): S=4096, N=32, E=512, H=8, DK=64. Query pos l = 2048 (L==1).
// qb = q.bk cancels in softmax (constant over s) -> dropped everywhere.
#define SS 4096
#define NB 32
#define EE 512
#define HH 8
#define DKK 64
#define LQ 2048
#define NCHUNK 32          // s-chunks per n (128 s each): grid 1024

// DPP cross-lane add: dst += perm(src) on the VALU pipe (no DS).
// 0xB1 quad_perm(1,0,3,2)=xor1; 0x4E quad_perm(2,3,0,1)=xor2;
// 0x141 ROW_HALF_MIRROR=xor7 (within 8); 0x128 ROW_ROR:8=xor8 (within 16).
#define DPPADD(dst, src, ctrl)                                              \
  dst += __int_as_float(__builtin_amdgcn_update_dpp(                        \
      0, __float_as_int(src), ctrl, 0xF, 0xF, true))

// Nontemporal float4 load: src is a read-once 268MB stream.
typedef float f32x4v __attribute__((ext_vector_type(4)));
__device__ __forceinline__ float4 ntload(const float4* p) {
  f32x4v t = __builtin_nontemporal_load((const f32x4v*)p);
  return make_float4(t.x, t.y, t.z, t.w);
}

// ---- K1: q[n,h,:] then qk[n,h,e] = sum_d q_d * Wk[h*64+d, e] ---------------
__global__ __launch_bounds__(256) void k_qproj(const float* __restrict__ src,
                                               const float* __restrict__ Wq,
                                               const float* __restrict__ bq,
                                               const float* __restrict__ Wk,
                                               float* __restrict__ qk) {
  __shared__ float qd[DKK];
  int n = blockIdx.x >> 3, h = blockIdx.x & 7;
  int tid = threadIdx.x;
  int d = tid >> 2, part = tid & 3;
  const float4* xs = (const float4*)(src + ((size_t)LQ * NB + n) * EE);
  const float4* wr = (const float4*)(Wq + (size_t)(h * DKK + d) * EE);
  float acc = 0.f;
#pragma unroll 8
  for (int i = 0; i < 32; ++i) {
    float4 a = xs[part * 32 + i], b = wr[part * 32 + i];
    acc = fmaf(a.x, b.x, fmaf(a.y, b.y, fmaf(a.z, b.z, fmaf(a.w, b.w, acc))));
  }
  DPPADD(acc, acc, 0xB1);   // xor1
  DPPADD(acc, acc, 0x4E);   // xor2
  if (part == 0) qd[d] = acc + bq[h * DKK + d];
  __syncthreads();
  float a0 = 0.f, a1 = 0.f;
#pragma unroll 8
  for (int d2 = 0; d2 < DKK; ++d2) {
    float qv = qd[d2];
    const float* row = Wk + (size_t)(h * DKK + d2) * EE;
    a0 = fmaf(qv, row[tid], a0);
    a1 = fmaf(qv, row[tid + 256], a1);
  }
  size_t base = (size_t)(n * HH + h) * EE;
  qk[base + tid] = a0;
  qk[base + tid + 256] = a1;
}

// ---- K2 (fused): one pass over src; 2 rows/wave-iter, prefetch-1, nt loads.
// CHANGE vs 80.0us best: qk fragments live in LDS (qks4, 16KB) instead of 64
// VGPRs -> register state ~124 <= 128 -> 4 blocks/CU (16 waves/CU) at grid
// 1024. Doubles resident waves issuing independent loads. acc stays in regs.
__global__ __launch_bounds__(256, 4) void k_fused(const float* __restrict__ src,
                                                  const float* __restrict__ qk,
                                                  float* __restrict__ part,
                                                  float* __restrict__ lw) {
  __shared__ float4 qks4[HH * 128];  // 16 KB: qk[n] tile, read-only in loop
  __shared__ float cbuf[HH * EE];    // 16 KB: epilogue combine
  __shared__ float lbuf[4 * HH];
  int b = blockIdx.x;
  int n = b >> 5, c = b & 31;
  int tid = threadIdx.x, wave = tid >> 6, lane = tid & 63;

  const int SLOT[8] = {0, 1, 2, 3, 7, 6, 5, 4};
  // stage qk[n] tile into LDS (coalesced, 4 float4/thread)
  {
    const float4* qk4 = (const float4*)qk + (size_t)n * (HH * 128);
#pragma unroll
    for (int i = 0; i < 4; ++i) qks4[tid + i * 256] = qk4[tid + i * 256];
  }
  __syncthreads();

  float4 acc[16];   // head-major: acc[2h], acc[2h+1]
#pragma unroll
  for (int i = 0; i < 16; ++i) acc[i] = make_float4(0.f, 0.f, 0.f, 0.f);
  float lp = 0.f;

  const size_t rowstep = (size_t)NB * (EE / 4);   // float4 step for s+1
  const float4* sp = (const float4*)src +
                     ((size_t)((c << 7) + wave * 2) * NB + n) * (EE / 4);
  float4 nA0 = ntload(sp + lane), nA1 = ntload(sp + 64 + lane);
  float4 nB0 = ntload(sp + rowstep + lane), nB1 = ntload(sp + rowstep + 64 + lane);

  for (int it = 0; it < 16; ++it) {
    float4 aA = nA0, dA = nA1, aB = nB0, dB = nB1;
    if (it < 15) {
      sp += 8 * rowstep;
      nA0 = ntload(sp + lane); nA1 = ntload(sp + 64 + lane);
      nB0 = ntload(sp + rowstep + lane); nB1 = ntload(sp + rowstep + 64 + lane);
    }
    float pA[8], pB[8];
#pragma unroll
    for (int j = 0; j < HH; ++j) {
      int hj = (lane & 7) ^ SLOT[j];
      float4 u = qks4[hj * 128 + lane];
      float4 v = qks4[hj * 128 + 64 + lane];
      pA[j] = fmaf(aA.x, u.x, fmaf(aA.y, u.y, fmaf(aA.z, u.z, fmaf(aA.w, u.w,
              fmaf(dA.x, v.x, fmaf(dA.y, v.y, fmaf(dA.z, v.z, dA.w * v.w)))))));
      pB[j] = fmaf(aB.x, u.x, fmaf(aB.y, u.y, fmaf(aB.z, u.z, fmaf(aB.w, u.w,
              fmaf(dB.x, v.x, fmaf(dB.y, v.y, fmaf(dB.z, v.z, dB.w * v.w)))))));
    }
    DPPADD(pA[0], pA[1], 0xB1);  DPPADD(pB[0], pB[1], 0xB1);
    DPPADD(pA[2], pA[3], 0xB1);  DPPADD(pB[2], pB[3], 0xB1);
    DPPADD(pA[4], pA[5], 0xB1);  DPPADD(pB[4], pB[5], 0xB1);
    DPPADD(pA[6], pA[7], 0xB1);  DPPADD(pB[6], pB[7], 0xB1);
    DPPADD(pA[0], pA[2], 0x4E);  DPPADD(pB[0], pB[2], 0x4E);
    DPPADD(pA[4], pA[6], 0x4E);  DPPADD(pB[4], pB[6], 0x4E);
    DPPADD(pA[0], pA[4], 0x141); DPPADD(pB[0], pB[4], 0x141);
    DPPADD(pA[0], pA[0], 0x128); DPPADD(pB[0], pB[0], 0x128);
    pA[0] += __shfl_xor(pA[0], 16, 64);
    pB[0] += __shfl_xor(pB[0], 16, 64);
    pA[0] += __shfl_xor(pA[0], 32, 64);
    pB[0] += __shfl_xor(pB[0], 32, 64);
    float eA = __expf(pA[0] * 0.125f);
    float eB = __expf(pB[0] * 0.125f);
    lp += eA + eB;
    float wA[8], wB[8];
#pragma unroll
    for (int h = 0; h < HH; ++h) {
      wA[h] = __uint_as_float(__builtin_amdgcn_readlane(__float_as_uint(eA), h));
      wB[h] = __uint_as_float(__builtin_amdgcn_readlane(__float_as_uint(eB), h));
    }
#pragma unroll
    for (int h = 0; h < HH; ++h) {
      float w1 = wA[h], w2 = wB[h];
      acc[2 * h].x = fmaf(w1, aA.x, acc[2 * h].x);
      acc[2 * h].y = fmaf(w1, aA.y, acc[2 * h].y);
      acc[2 * h].z = fmaf(w1, aA.z, acc[2 * h].z);
      acc[2 * h].w = fmaf(w1, aA.w, acc[2 * h].w);
      acc[2 * h + 1].x = fmaf(w1, dA.x, acc[2 * h + 1].x);
      acc[2 * h + 1].y = fmaf(w1, dA.y, acc[2 * h + 1].y);
      acc[2 * h + 1].z = fmaf(w1, dA.z, acc[2 * h + 1].z);
      acc[2 * h + 1].w = fmaf(w1, dA.w, acc[2 * h + 1].w);
      acc[2 * h].x = fmaf(w2, aB.x, acc[2 * h].x);
      acc[2 * h].y = fmaf(w2, aB.y, acc[2 * h].y);
      acc[2 * h].z = fmaf(w2, aB.z, acc[2 * h].z);
      acc[2 * h].w = fmaf(w2, aB.w, acc[2 * h].w);
      acc[2 * h + 1].x = fmaf(w2, dB.x, acc[2 * h + 1].x);
      acc[2 * h + 1].y = fmaf(w2, dB.y, acc[2 * h + 1].y);
      acc[2 * h + 1].z = fmaf(w2, dB.z, acc[2 * h + 1].z);
      acc[2 * h + 1].w = fmaf(w2, dB.w, acc[2 * h + 1].w);
    }
  }

  if (lane < 8) lbuf[wave * 8 + lane] = lp;

  for (int i = tid; i < HH * EE; i += 256) cbuf[i] = 0.f;
  __syncthreads();
  for (int w4 = 0; w4 < 4; ++w4) {
    if (wave == w4) {
#pragma unroll
      for (int h = 0; h < HH; ++h) {
        int e0 = h * EE + 4 * lane;
        cbuf[e0 + 0] += acc[2 * h].x;
        cbuf[e0 + 1] += acc[2 * h].y;
        cbuf[e0 + 2] += acc[2 * h].z;
        cbuf[e0 + 3] += acc[2 * h].w;
        int e1 = e0 + 256;
        cbuf[e1 + 0] += acc[2 * h + 1].x;
        cbuf[e1 + 1] += acc[2 * h + 1].y;
        cbuf[e1 + 2] += acc[2 * h + 1].z;
        cbuf[e1 + 3] += acc[2 * h + 1].w;
      }
    }
    __syncthreads();
  }
  float* pb = part + (size_t)b * (HH * EE);
  for (int i = tid; i < HH * EE; i += 256) pb[i] = cbuf[i];
  if (tid < 8)
    lw[b * 8 + tid] = lbuf[tid] + lbuf[8 + tid] + lbuf[16 + tid] + lbuf[24 + tid];
}

// ---- K3: ctx[n*8+h][e] = (sum_c part) / (sum_c lw)  ------------------------
__global__ __launch_bounds__(256) void k_combine(const float* __restrict__ part,
                                                 const float* __restrict__ lw,
                                                 float* __restrict__ ctx) {
  int t = blockIdx.x * 256 + threadIdx.x;  // 131072
  int n = t >> 12, x = t & 4095, h = x >> 9;
  float s = 0.f, lt = 0.f;
#pragma unroll
  for (int c = 0; c < NCHUNK; ++c) {
    int b = n * NCHUNK + c;
    s += part[(size_t)b * 4096 + x];
    lt += lw[b * 8 + h];
  }
  ctx[t] = s / lt;
}

// ---- K4-K6: wide GEMV. y[n,r] = x[row(n,r), :] . W[r,:] + b[r].
// Grid 2048 = (r, n-octet g); 1 wave. W row coalesced (64 lanes x float4 x 2).
// 8 outputs per wave via DPP slot-fold (masks 1,2,7 + xor8/16/32).
// HMAP=1: x rows are ctx[n*8+h] with h = r>>6 (Wv stage); else x rows = n.
template <int HMAP>
__global__ __launch_bounds__(64) void k_gemv(const float* __restrict__ x,
                                             const float* __restrict__ W,
                                             const float* __restrict__ bias,
                                             float* __restrict__ y) {
  int r = blockIdx.x >> 2, g = blockIdx.x & 3;
  int lane = threadIdx.x;
  const float4* W4 = (const float4*)W;
  const float4* x4 = (const float4*)x;
  float4 w0 = W4[r * 128 + lane];
  float4 w1 = W4[r * 128 + 64 + lane];
  const int SLOT[8] = {0, 1, 2, 3, 7, 6, 5, 4};
  float acc[8];
#pragma unroll
  for (int j = 0; j < 8; ++j) {
    int n = g * 8 + ((lane & 7) ^ SLOT[j]);
    int row = HMAP ? (n * 8 + (r >> 6)) : n;
    float4 a = x4[row * 128 + lane], d = x4[row * 128 + 64 + lane];
    acc[j] = fmaf(a.x, w0.x, fmaf(a.y, w0.y, fmaf(a.z, w0.z, fmaf(a.w, w0.w,
             fmaf(d.x, w1.x, fmaf(d.y, w1.y, fmaf(d.z, w1.z, d.w * w1.w)))))));
  }
  DPPADD(acc[0], acc[1], 0xB1);
  DPPADD(acc[2], acc[3], 0xB1);
  DPPADD(acc[4], acc[5], 0xB1);
  DPPADD(acc[6], acc[7], 0xB1);
  DPPADD(acc[0], acc[2], 0x4E);
  DPPADD(acc[4], acc[6], 0x4E);
  DPPADD(acc[0], acc[4], 0x141);
  DPPADD(acc[0], acc[0], 0x128);
  acc[0] += __shfl_xor(acc[0], 16, 64);
  acc[0] += __shfl_xor(acc[0], 32, 64);
  if (lane < 8) y[(size_t)(g * 8 + lane) * EE + r] = acc[0] + bias[r];
}

extern "C" void kernel_launch(void* const* d_in, const int* in_sizes, int n_in,
                              void* d_out, int out_size, void* d_ws, size_t ws_size,
                              hipStream_t stream) {
  const float* src = (const float*)d_in[0];
  const float* Wq  = (const float*)d_in[1];
  const float* bq  = (const float*)d_in[2];
  const float* Wk  = (const float*)d_in[3];
  const float* Wv  = (const float*)d_in[5];
  const float* bv  = (const float*)d_in[6];
  const float* Wo  = (const float*)d_in[7];
  const float* bo  = (const float*)d_in[8];
  const float* Wl  = (const float*)d_in[9];
  const float* bl  = (const float*)d_in[10];
  float* out = (float*)d_out;

  float* ws = (float*)d_ws;
  float* qk   = ws;                               // 131072
  float* lw   = qk + 131072;                      // 1024*8 = 8192
  float* ctx  = lw + 8192;                        // 131072
  float* vout = ctx + 131072;                     // 16384
  float* y1   = vout + 16384;                     // 16384
  float* part = y1 + 16384;                       // 1024*4096 floats (16MB)

  k_qproj<<<256, 256, 0, stream>>>(src, Wq, bq, Wk, qk);
  k_fused<<<NB * NCHUNK, 256, 0, stream>>>(src, qk, part, lw);
  k_combine<<<512, 256, 0, stream>>>(part, lw, ctx);
  k_gemv<1><<<2048, 64, 0, stream>>>(ctx, Wv, bv, vout);
  k_gemv<0><<<2048, 64, 0, stream>>>(vout, Wo, bo, y1);
  k_gemv<0><<<2048, 64, 0, stream>>>(y1, Wl, bl, out);
}

// Round 17
// 80.367 us; speedup vs baseline: 5.8561x; 5.8561x over previous
//
#include <hip/hip_runtime.h>

// Dims (fixed): S=4096, N=32, E=512, H=8, DK=64. Query pos l = 2048 (L==1).
// qb = q.bk cancels in softmax (constant over s) -> dropped everywhere.
#define SS 4096
#define NB 32
#define EE 512
#define HH 8
#define DKK 64
#define LQ 2048
#define NCHUNK 16          // s-chunks per n in fused kernel (256 s each)

// DPP cross-lane add: dst += perm(src) on the VALU pipe (no DS).
// 0xB1 quad_perm(1,0,3,2)=xor1; 0x4E quad_perm(2,3,0,1)=xor2;
// 0x141 ROW_HALF_MIRROR=xor7 (within 8); 0x128 ROW_ROR:8=xor8 (within 16).
#define DPPADD(dst, src, ctrl)                                              \
  dst += __int_as_float(__builtin_amdgcn_update_dpp(                        \
      0, __float_as_int(src), ctrl, 0xF, 0xF, true))

// Nontemporal float4 load: src is a read-once 268MB stream -> nt bit keeps
// it from polluting L1/L2 (qk/part stay hot).
typedef float f32x4v __attribute__((ext_vector_type(4)));
__device__ __forceinline__ float4 ntload(const float4* p) {
  f32x4v t = __builtin_nontemporal_load((const f32x4v*)p);
  return make_float4(t.x, t.y, t.z, t.w);
}

// ---- K1: q[n,h,:] then qk[n,h,e] = sum_d q_d * Wk[h*64+d, e] ---------------
__global__ __launch_bounds__(256) void k_qproj(const float* __restrict__ src,
                                               const float* __restrict__ Wq,
                                               const float* __restrict__ bq,
                                               const float* __restrict__ Wk,
                                               float* __restrict__ qk) {
  __shared__ float qd[DKK];
  int n = blockIdx.x >> 3, h = blockIdx.x & 7;
  int tid = threadIdx.x;
  int d = tid >> 2, part = tid & 3;
  const float4* xs = (const float4*)(src + ((size_t)LQ * NB + n) * EE);
  const float4* wr = (const float4*)(Wq + (size_t)(h * DKK + d) * EE);
  float acc = 0.f;
#pragma unroll 8
  for (int i = 0; i < 32; ++i) {
    float4 a = xs[part * 32 + i], b = wr[part * 32 + i];
    acc = fmaf(a.x, b.x, fmaf(a.y, b.y, fmaf(a.z, b.z, fmaf(a.w, b.w, acc))));
  }
  DPPADD(acc, acc, 0xB1);   // xor1
  DPPADD(acc, acc, 0x4E);   // xor2
  if (part == 0) qd[d] = acc + bq[h * DKK + d];
  __syncthreads();
  float a0 = 0.f, a1 = 0.f;
#pragma unroll 8
  for (int d2 = 0; d2 < DKK; ++d2) {
    float qv = qd[d2];
    const float* row = Wk + (size_t)(h * DKK + d2) * EE;
    a0 = fmaf(qv, row[tid], a0);
    a1 = fmaf(qv, row[tid + 256], a1);
  }
  size_t base = (size_t)(n * HH + h) * EE;
  qk[base + tid] = a0;
  qk[base + tid + 256] = a1;
}

// ---- K2 (fused): one pass over src; 2 rows/wave-iter (ILP).
// Slot offsets s = {0,1,2,3,7,6,5,4}: slot j of lane L holds head (L&7)^s_j.
// Fold uses DPP masks {1,2,7,8} + shfl {16,32}. Lane L ends with the full dot
// for head L&7; weights wave-uniform -> readlane to SGPR. src via nt loads.
// Pinned at 2 blocks/CU: acc[16]x4 = 64 VGPR live accumulator; any
// launch_bounds occupancy request beyond (256,2) spills catastrophically
// (R15/R16: VGPR cliffs to 64, 800+MB scratch traffic).
__global__ __launch_bounds__(256, 2) void k_fused(const float* __restrict__ src,
                                                  const float* __restrict__ qk,
                                                  float* __restrict__ part,
                                                  float* __restrict__ lw) {
  __shared__ float cbuf[HH * EE];   // 16 KB
  __shared__ float lbuf[4 * HH];
  int b = blockIdx.x;
  int n = b >> 4, c = b & 15;
  int tid = threadIdx.x, wave = tid >> 6, lane = tid & 63;

  const int SLOT[8] = {0, 1, 2, 3, 7, 6, 5, 4};
  const float4* qk4 = (const float4*)qk;
  float4 qf[16];
#pragma unroll
  for (int j = 0; j < HH; ++j) {
    int hj = (lane & 7) ^ SLOT[j];
    int qbase = (n * HH + hj) * (EE / 4);
    qf[2 * j] = qk4[qbase + lane];
    qf[2 * j + 1] = qk4[qbase + 64 + lane];
  }

  float4 acc[16];   // head-major: acc[2h], acc[2h+1]
#pragma unroll
  for (int i = 0; i < 16; ++i) acc[i] = make_float4(0.f, 0.f, 0.f, 0.f);
  float lp = 0.f;

  const size_t rowstep = (size_t)NB * (EE / 4);   // float4 step for s+1
  const float4* sp = (const float4*)src +
                     ((size_t)((c << 8) + wave * 2) * NB + n) * (EE / 4);
  float4 nA0 = ntload(sp + lane), nA1 = ntload(sp + 64 + lane);
  float4 nB0 = ntload(sp + rowstep + lane), nB1 = ntload(sp + rowstep + 64 + lane);

  for (int it = 0; it < 32; ++it) {
    float4 aA = nA0, dA = nA1, aB = nB0, dB = nB1;
    if (it < 31) {
      sp += 8 * rowstep;
      nA0 = ntload(sp + lane); nA1 = ntload(sp + 64 + lane);
      nB0 = ntload(sp + rowstep + lane); nB1 = ntload(sp + rowstep + 64 + lane);
    }
    float pA[8], pB[8];
#pragma unroll
    for (int j = 0; j < HH; ++j) {
      float4 u = qf[2 * j], v = qf[2 * j + 1];
      pA[j] = fmaf(aA.x, u.x, fmaf(aA.y, u.y, fmaf(aA.z, u.z, fmaf(aA.w, u.w,
              fmaf(dA.x, v.x, fmaf(dA.y, v.y, fmaf(dA.z, v.z, dA.w * v.w)))))));
      pB[j] = fmaf(aB.x, u.x, fmaf(aB.y, u.y, fmaf(aB.z, u.z, fmaf(aB.w, u.w,
              fmaf(dB.x, v.x, fmaf(dB.y, v.y, fmaf(dB.z, v.z, dB.w * v.w)))))));
    }
    DPPADD(pA[0], pA[1], 0xB1);  DPPADD(pB[0], pB[1], 0xB1);
    DPPADD(pA[2], pA[3], 0xB1);  DPPADD(pB[2], pB[3], 0xB1);
    DPPADD(pA[4], pA[5], 0xB1);  DPPADD(pB[4], pB[5], 0xB1);
    DPPADD(pA[6], pA[7], 0xB1);  DPPADD(pB[6], pB[7], 0xB1);
    DPPADD(pA[0], pA[2], 0x4E);  DPPADD(pB[0], pB[2], 0x4E);
    DPPADD(pA[4], pA[6], 0x4E);  DPPADD(pB[4], pB[6], 0x4E);
    DPPADD(pA[0], pA[4], 0x141); DPPADD(pB[0], pB[4], 0x141);
    DPPADD(pA[0], pA[0], 0x128); DPPADD(pB[0], pB[0], 0x128);
    pA[0] += __shfl_xor(pA[0], 16, 64);
    pB[0] += __shfl_xor(pB[0], 16, 64);
    pA[0] += __shfl_xor(pA[0], 32, 64);
    pB[0] += __shfl_xor(pB[0], 32, 64);
    float eA = __expf(pA[0] * 0.125f);
    float eB = __expf(pB[0] * 0.125f);
    lp += eA + eB;
    float wA[8], wB[8];
#pragma unroll
    for (int h = 0; h < HH; ++h) {
      wA[h] = __uint_as_float(__builtin_amdgcn_readlane(__float_as_uint(eA), h));
      wB[h] = __uint_as_float(__builtin_amdgcn_readlane(__float_as_uint(eB), h));
    }
#pragma unroll
    for (int h = 0; h < HH; ++h) {
      float w1 = wA[h], w2 = wB[h];
      acc[2 * h].x = fmaf(w1, aA.x, acc[2 * h].x);
      acc[2 * h].y = fmaf(w1, aA.y, acc[2 * h].y);
      acc[2 * h].z = fmaf(w1, aA.z, acc[2 * h].z);
      acc[2 * h].w = fmaf(w1, aA.w, acc[2 * h].w);
      acc[2 * h + 1].x = fmaf(w1, dA.x, acc[2 * h + 1].x);
      acc[2 * h + 1].y = fmaf(w1, dA.y, acc[2 * h + 1].y);
      acc[2 * h + 1].z = fmaf(w1, dA.z, acc[2 * h + 1].z);
      acc[2 * h + 1].w = fmaf(w1, dA.w, acc[2 * h + 1].w);
      acc[2 * h].x = fmaf(w2, aB.x, acc[2 * h].x);
      acc[2 * h].y = fmaf(w2, aB.y, acc[2 * h].y);
      acc[2 * h].z = fmaf(w2, aB.z, acc[2 * h].z);
      acc[2 * h].w = fmaf(w2, aB.w, acc[2 * h].w);
      acc[2 * h + 1].x = fmaf(w2, dB.x, acc[2 * h + 1].x);
      acc[2 * h + 1].y = fmaf(w2, dB.y, acc[2 * h + 1].y);
      acc[2 * h + 1].z = fmaf(w2, dB.z, acc[2 * h + 1].z);
      acc[2 * h + 1].w = fmaf(w2, dB.w, acc[2 * h + 1].w);
    }
  }

  if (lane < 8) lbuf[wave * 8 + lane] = lp;

  for (int i = tid; i < HH * EE; i += 256) cbuf[i] = 0.f;
  __syncthreads();
  for (int w4 = 0; w4 < 4; ++w4) {
    if (wave == w4) {
#pragma unroll
      for (int h = 0; h < HH; ++h) {
        int e0 = h * EE + 4 * lane;
        cbuf[e0 + 0] += acc[2 * h].x;
        cbuf[e0 + 1] += acc[2 * h].y;
        cbuf[e0 + 2] += acc[2 * h].z;
        cbuf[e0 + 3] += acc[2 * h].w;
        int e1 = e0 + 256;
        cbuf[e1 + 0] += acc[2 * h + 1].x;
        cbuf[e1 + 1] += acc[2 * h + 1].y;
        cbuf[e1 + 2] += acc[2 * h + 1].z;
        cbuf[e1 + 3] += acc[2 * h + 1].w;
      }
    }
    __syncthreads();
  }
  float* pb = part + (size_t)b * (HH * EE);
  for (int i = tid; i < HH * EE; i += 256) pb[i] = cbuf[i];
  if (tid < 8)
    lw[b * 8 + tid] = lbuf[tid] + lbuf[8 + tid] + lbuf[16 + tid] + lbuf[24 + tid];
}

// ---- K3: ctx[n*8+h][e] = (sum_c part) / (sum_c lw)  ------------------------
__global__ __launch_bounds__(256) void k_combine(const float* __restrict__ part,
                                                 const float* __restrict__ lw,
                                                 float* __restrict__ ctx) {
  int t = blockIdx.x * 256 + threadIdx.x;  // 131072
  int n = t >> 12, x = t & 4095, h = x >> 9;
  float s = 0.f, lt = 0.f;
#pragma unroll
  for (int c = 0; c < NCHUNK; ++c) {
    s += part[(size_t)(n * NCHUNK + c) * 4096 + x];
    lt += lw[(n * NCHUNK + c) * 8 + h];
  }
  ctx[t] = s / lt;
}

// ---- K4-K6: wide GEMV. y[n,r] = x[row(n,r), :] . W[r,:] + b[r].
// Grid 2048 = (r, n-octet g); 1 wave. W row coalesced (64 lanes x float4 x 2).
// 8 outputs per wave via DPP slot-fold (masks 1,2,7 + xor8/16/32).
// HMAP=1: x rows are ctx[n*8+h] with h = r>>6 (Wv stage); else x rows = n.
template <int HMAP>
__global__ __launch_bounds__(64) void k_gemv(const float* __restrict__ x,
                                             const float* __restrict__ W,
                                             const float* __restrict__ bias,
                                             float* __restrict__ y) {
  int r = blockIdx.x >> 2, g = blockIdx.x & 3;
  int lane = threadIdx.x;
  const float4* W4 = (const float4*)W;
  const float4* x4 = (const float4*)x;
  float4 w0 = W4[r * 128 + lane];
  float4 w1 = W4[r * 128 + 64 + lane];
  const int SLOT[8] = {0, 1, 2, 3, 7, 6, 5, 4};
  float acc[8];
#pragma unroll
  for (int j = 0; j < 8; ++j) {
    int n = g * 8 + ((lane & 7) ^ SLOT[j]);
    int row = HMAP ? (n * 8 + (r >> 6)) : n;
    float4 a = x4[row * 128 + lane], d = x4[row * 128 + 64 + lane];
    acc[j] = fmaf(a.x, w0.x, fmaf(a.y, w0.y, fmaf(a.z, w0.z, fmaf(a.w, w0.w,
             fmaf(d.x, w1.x, fmaf(d.y, w1.y, fmaf(d.z, w1.z, d.w * w1.w)))))));
  }
  DPPADD(acc[0], acc[1], 0xB1);
  DPPADD(acc[2], acc[3], 0xB1);
  DPPADD(acc[4], acc[5], 0xB1);
  DPPADD(acc[6], acc[7], 0xB1);
  DPPADD(acc[0], acc[2], 0x4E);
  DPPADD(acc[4], acc[6], 0x4E);
  DPPADD(acc[0], acc[4], 0x141);
  DPPADD(acc[0], acc[0], 0x128);
  acc[0] += __shfl_xor(acc[0], 16, 64);
  acc[0] += __shfl_xor(acc[0], 32, 64);
  if (lane < 8) y[(size_t)(g * 8 + lane) * EE + r] = acc[0] + bias[r];
}

extern "C" void kernel_launch(void* const* d_in, const int* in_sizes, int n_in,
                              void* d_out, int out_size, void* d_ws, size_t ws_size,
                              hipStream_t stream) {
  const float* src = (const float*)d_in[0];
  const float* Wq  = (const float*)d_in[1];
  const float* bq  = (const float*)d_in[2];
  const float* Wk  = (const float*)d_in[3];
  const float* Wv  = (const float*)d_in[5];
  const float* bv  = (const float*)d_in[6];
  const float* Wo  = (const float*)d_in[7];
  const float* bo  = (const float*)d_in[8];
  const float* Wl  = (const float*)d_in[9];
  const float* bl  = (const float*)d_in[10];
  float* out = (float*)d_out;

  float* ws = (float*)d_ws;
  float* qk   = ws;                               // 131072
  float* lw   = qk + 131072;                      // 512*8 = 4096
  float* ctx  = lw + 4096;                        // 131072
  float* vout = ctx + 131072;                     // 16384
  float* y1   = vout + 16384;                     // 16384
  float* part = y1 + 16384;                       // 512*4096 floats (8MB)

  k_qproj<<<256, 256, 0, stream>>>(src, Wq, bq, Wk, qk);
  k_fused<<<NB * NCHUNK, 256, 0, stream>>>(src, qk, part, lw);
  k_combine<<<512, 256, 0, stream>>>(part, lw, ctx);
  k_gemv<1><<<2048, 64, 0, stream>>>(ctx, Wv, bv, vout);
  k_gemv<0><<<2048, 64, 0, stream>>>(vout, Wo, bo, y1);
  k_gemv<0><<<2048, 64, 0, stream>>>(y1, Wl, bl, out);
}